// Round 16
// baseline (285.172 us; speedup 1.0000x reference)
//
#include <hip/hip_runtime.h>
#include <stdint.h>

#define NB 4096
#define NT 48
#define NF 225
#define NH 128
#define NG 512   // 4*H
#define NK 256   // K padded 225->256
#define NCLS 100

typedef __attribute__((ext_vector_type(8))) _Float16 v8h;
typedef __attribute__((ext_vector_type(4))) _Float16 v4h;
typedef __attribute__((ext_vector_type(4))) float v4f;

__device__ __forceinline__ float fsig(float x) {
    return __builtin_amdgcn_rcpf(1.f + __expf(-x));
}
__device__ __forceinline__ float ftanh(float x) {
    return 2.f * __builtin_amdgcn_rcpf(1.f + __expf(-2.f * x)) - 1.f;
}
// keep loop-invariant LDS-B addresses from being hoisted (register budget!)
__device__ __forceinline__ int opq(int x) { asm volatile("" : "+v"(x)); return x; }
// hb swizzle key: write side maps grp-quad {r,4+r,8+r,12+r} to 4 distinct
// values mod 8 (r11's b&7 collapsed to 2 -> 4-way conflict); read side is
// 8-value-bijective over rows 0-7 and 8-15 -> 2 lanes/16B slot (free).
__device__ __forceinline__ int fkey(int v) { return (v ^ (v >> 2)) & 7; }

// MFMA via inline asm: acc in VGPR, B pinned in AGPR (non-rematerializable)
__device__ __forceinline__ void mfma_ba(v4f& c, v8h a, v8h b) {
    asm volatile("v_mfma_f32_16x16x32_f16 %0, %1, %2, %0"
                 : "+v"(c) : "v"(a), "a"(b));
}
// MFMA with B streamed from LDS (VGPR)
__device__ __forceinline__ void mfma_bv(v4f& c, v8h a, v8h b) {
    asm volatile("v_mfma_f32_16x16x32_f16 %0, %1, %2, %0"
                 : "+v"(c) : "v"(a), "v"(b));
}

// global -> LDS direct copy, 16B per lane (dest = wave-uniform base + lane*16).
__device__ __forceinline__ void gld16(const void* g, void* l) {
    __builtin_amdgcn_global_load_lds(
        (const __attribute__((address_space(1))) void*)g,
        (__attribute__((address_space(3))) void*)l, 16, 0, 0);
}

// ---------------------------------------------------------------------------
// k_prep:
//  xh[t][b][256]   fp16, zero-padded, 16B chunks XOR-swizzled by (b&7)
//  wt[dir][8ks][4grp][384n][8]  k-major transposed w_ih (gates i,f,g) fp16
//  wht[dir][4ks][4grp][384n][8] k-major transposed w_hh (gates i,f,g) fp16
//  wh3[dir][128][256]  gate-o w_ih rows, chunk-swizzled by (col&7)  (LDS copy)
//  whh3[dir][128][128] gate-o w_hh rows, chunk-swizzled by (col&7)
//  bsum[dir][512] = b_ih + b_hh (fp32)
// ---------------------------------------------------------------------------
__global__ __launch_bounds__(256) void k_prep(
    const float* __restrict__ x,
    const float* __restrict__ wihf, const float* __restrict__ wihb,
    const float* __restrict__ whhf, const float* __restrict__ whhb,
    const float* __restrict__ bihf, const float* __restrict__ bhhf,
    const float* __restrict__ bihb, const float* __restrict__ bhhb,
    _Float16* __restrict__ xh, _Float16* __restrict__ wt,
    _Float16* __restrict__ wht, _Float16* __restrict__ wh3,
    _Float16* __restrict__ whh3, float* __restrict__ bsum)
{
    __shared__ __attribute__((aligned(16))) _Float16 ls[NT * NF + 16];
    const int bid = blockIdx.x;
    const int tid = threadIdx.x;

    if (bid < NB) {
        const float* src = x + (size_t)bid * (NT * NF);   // 43200B contiguous
        for (int i = tid; i < (NT * NF) / 4; i += 256) {
            const float4 v = ((const float4*)src)[i];
            v4h hv; hv[0] = (_Float16)v.x; hv[1] = (_Float16)v.y;
            hv[2] = (_Float16)v.z; hv[3] = (_Float16)v.w;
            *(v4h*)(ls + i * 4) = hv;
        }
        __syncthreads();
        const int key = bid & 7;
        for (int task = tid; task < NT * 32; task += 256) {
            const int t = task >> 5, c = task & 31;
            v8h hv;
#pragma unroll
            for (int e = 0; e < 8; ++e) {
                const int k = c * 8 + e;
                hv[e] = (k < NF) ? ls[t * NF + k] : (_Float16)0.f;
            }
            *(v8h*)(xh + ((size_t)t * NB + bid) * NK + ((c ^ key) << 3)) = hv;
        }
    } else if (bid < NB + 96) {
        // wt: 24576 v8h rows [dir][ks 0..7][grp 0..3][n 0..383]
        const int task = (bid - NB) * 256 + tid;
        const int n = task % 384;
        const int r2 = task / 384;          // 0..63
        const int grp = r2 & 3, ks = (r2 >> 2) & 7, dir = r2 >> 5;
        const float* src = (dir ? wihb : wihf) + (size_t)n * NF;
        v8h hv;
#pragma unroll
        for (int e = 0; e < 8; ++e) {
            const int k = ks * 32 + grp * 8 + e;
            hv[e] = (k < NF) ? (_Float16)src[k] : (_Float16)0.f;
        }
        *(v8h*)(wt + (size_t)task * 8) = hv;
    } else if (bid < NB + 144) {
        // wht: 12288 v8h rows [dir][ks 0..3][grp 0..3][n 0..383]
        const int task = (bid - NB - 96) * 256 + tid;
        const int n = task % 384;
        const int r2 = task / 384;          // 0..31
        const int grp = r2 & 3, ks = (r2 >> 2) & 3, dir = r2 >> 4;
        const float* src = (dir ? whhb : whhf) + (size_t)n * NH + ks * 32 + grp * 8;
        v8h hv;
#pragma unroll
        for (int e = 0; e < 8; ++e) hv[e] = (_Float16)src[e];
        *(v8h*)(wht + (size_t)task * 8) = hv;
    } else if (bid < NB + 148) {
        // wh3: gate-o (rows 384..511) of w_ih, chunk-swizzled by (col&7)
        for (int s = 0; s < 8; ++s) {
            const int task = (bid - NB - 144) * 2048 + s * 256 + tid; // 0..8191
            const int dir = task >> 12;
            const int rem = task & 4095;
            const int col = rem >> 5, c = rem & 31;
            const float* src = (dir ? wihb : wihf) + (size_t)(384 + col) * NF + c * 8;
            v8h hv;
#pragma unroll
            for (int e = 0; e < 8; ++e) {
                const int k = c * 8 + e;
                hv[e] = (k < NF) ? (_Float16)src[e] : (_Float16)0.f;
            }
            *(v8h*)(wh3 + ((size_t)dir * 128 + col) * NK + ((c ^ (col & 7)) << 3)) = hv;
        }
    } else if (bid < NB + 150) {
        // whh3: gate-o (rows 384..511) of w_hh, chunk-swizzled by (col&7)
        for (int s = 0; s < 8; ++s) {
            const int task = (bid - NB - 148) * 2048 + s * 256 + tid; // 0..4095
            const int dir = task >> 11;
            const int rem = task & 2047;
            const int col = rem >> 4, c = rem & 15;
            const float* src = (dir ? whhb : whhf) + (size_t)(384 + col) * NH + c * 8;
            v8h hv;
#pragma unroll
            for (int e = 0; e < 8; ++e) hv[e] = (_Float16)src[e];
            *(v8h*)(whh3 + ((size_t)dir * 128 + col) * NH + ((c ^ (col & 7)) << 3)) = hv;
        }
    } else {
        for (int i = tid; i < 1024; i += 256) {
            const int dir = i >> 9, n = i & 511;
            bsum[i] = dir ? (bihb[n] + bhhb[n]) : (bihf[n] + bhhf[n]);
        }
    }
}

// ---------------------------------------------------------------------------
// k_fused: input GEMM + LSTM recurrence + hsum, one dispatch.
// Identical to the verified 267us kernel EXCEPT the hb swizzle key is
// fkey(b) instead of b&7 (h-store was a 4-way bank conflict: grp0/grp2 and
// grp1/grp3 shared keys). bo-read keys and prep untouched (r12 lesson).
// ---------------------------------------------------------------------------
__global__ void __launch_bounds__(512, 2) k_fused(
    const _Float16* __restrict__ xh,     // [48][4096][256] swizzled (b&7)
    const _Float16* __restrict__ wt,     // [2][8][4][384][8]
    const _Float16* __restrict__ wht,    // [2][4][4][384][8]
    const _Float16* __restrict__ wh3,    // [2][128][256] swizzled (col&7)
    const _Float16* __restrict__ whh3,   // [2][128][128] swizzled (col&7)
    const float* __restrict__ bsum,      // [2][512]
    float* __restrict__ hsum)            // [2][4096][128]
{
    __shared__ __attribute__((aligned(16))) _Float16 xb[2][32 * 256]; // 32KB
    __shared__ __attribute__((aligned(16))) _Float16 hb[2][32 * 128]; // 16KB
    __shared__ __attribute__((aligned(16))) _Float16 bxo[128 * 256];  // 64KB
    __shared__ __attribute__((aligned(16))) _Float16 bho[128 * 128];  // 32KB

    const int tid   = threadIdx.x;
    const int btile = blockIdx.x;        // 0..127
    const int dir   = blockIdx.y;
    const int rb    = btile * 32;
    const int lane  = tid & 63;
    const int w     = tid >> 6;          // 0..7
    const int l15   = lane & 15;
    const int grp   = lane >> 4;
    const int hcol  = w * 16 + l15;      // 0..127
    const int swz   = hcol & 7;

    // one-time LDS preload of gate-o weights (pre-swizzled source, DMA)
#pragma unroll
    for (int j = 0; j < 12; ++j) {
        const int seg = w + j * 8;       // 0..95
        if (seg < 64)
            gld16((const char*)wh3 + (size_t)dir * 65536 + (seg << 10) + lane * 16,
                  (char*)bxo + (seg << 10));
        else
            gld16((const char*)whh3 + (size_t)dir * 32768 + ((seg - 64) << 10) + lane * 16,
                  (char*)bho + ((seg - 64) << 10));
    }

    // persistent B fragments: gates 0..2 (i,f,g), pinned into AGPRs once.
    v8h bx[3][8], bh[3][4];
#pragma unroll
    for (int g = 0; g < 3; ++g) {
#pragma unroll
        for (int ks = 0; ks < 8; ++ks) {
            bx[g][ks] = *(const v8h*)(wt +
                ((((size_t)dir * 8 + ks) * 4 + grp) * 384 + g * 128 + hcol) * 8);
            asm volatile("" : "+a"(bx[g][ks]));
        }
#pragma unroll
        for (int ks = 0; ks < 4; ++ks) {
            bh[g][ks] = *(const v8h*)(wht +
                ((((size_t)dir * 4 + ks) * 4 + grp) * 384 + g * 128 + hcol) * 8);
            asm volatile("" : "+a"(bh[g][ks]));
        }
    }
    float bias[4];
#pragma unroll
    for (int g = 0; g < 4; ++g)
        bias[g] = bsum[dir * NG + g * NH + hcol];

    float c0[2][4], hs0[2][4];
#pragma unroll
    for (int m = 0; m < 2; ++m)
#pragma unroll
        for (int r = 0; r < 4; ++r) { c0[m][r] = 0.f; hs0[m][r] = 0.f; }

    auto stage = [&](int tx, int buf) {
        const char* src = (const char*)(xh + ((size_t)tx * NB + rb) * NK);
#pragma unroll
        for (int c = 0; c < 2; ++c) {
            const int seg = w * 2 + c;            // 16 x 1KB segments
            gld16(src + (seg << 10) + lane * 16, (char*)xb[buf] + (seg << 10));
        }
    };

    stage(dir ? (NT - 1) : 0, 0);
    __syncthreads();   // preloads + stage drained

    int cur = 0, hc = 0;
#pragma unroll 1
    for (int t = 0; t < NT; ++t) {
        if (t + 1 < NT)
            stage(dir ? (NT - 2 - t) : (t + 1), cur ^ 1);   // async prefetch

        v4f acc[2][4];
#pragma unroll
        for (int m = 0; m < 2; ++m)
#pragma unroll
            for (int g = 0; g < 4; ++g)
                acc[m][g] = (v4f){bias[g], bias[g], bias[g], bias[g]};

        // fence: VALU acc-init -> MFMA srcC read (hazard recognizer can't
        // see into INLINEASM; carry all accs as operands to pin ordering)
        asm volatile("s_nop 2"
            : "+v"(acc[0][0]), "+v"(acc[0][1]), "+v"(acc[0][2]), "+v"(acc[0][3]),
              "+v"(acc[1][0]), "+v"(acc[1][1]), "+v"(acc[1][2]), "+v"(acc[1][3]));

        // x-part: K=256 in 8 slices; gates 0-2 AGPR-B, gate 3 LDS-B
#pragma unroll
        for (int ks = 0; ks < 8; ++ks) {
            const int ch = ((ks * 4 + grp) ^ swz) << 4;
            v8h af0 = *(const v8h*)((const char*)xb[cur] + (l15 << 9)
                        + ((((ks * 4 + grp) ^ (l15 & 7))) << 4));
            v8h af1 = *(const v8h*)((const char*)xb[cur] + ((16 + l15) << 9)
                        + ((((ks * 4 + grp) ^ (l15 & 7))) << 4));
            v8h bo = *(const v8h*)((const char*)bxo + opq((hcol << 9) + ch));
            mfma_ba(acc[0][0], af0, bx[0][ks]);
            mfma_ba(acc[1][0], af1, bx[0][ks]);
            mfma_ba(acc[0][1], af0, bx[1][ks]);
            mfma_ba(acc[1][1], af1, bx[1][ks]);
            mfma_ba(acc[0][2], af0, bx[2][ks]);
            mfma_ba(acc[1][2], af1, bx[2][ks]);
            mfma_bv(acc[0][3], af0, bo);
            mfma_bv(acc[1][3], af1, bo);
        }

        // h-part: K=128 in 4 slices (fkey-swizzled hb)
        if (t > 0) {
#pragma unroll
            for (int ks = 0; ks < 4; ++ks) {
                const int ch = ((ks * 4 + grp) ^ swz) << 4;
                v8h ah0 = *(const v8h*)((const char*)hb[hc] + (l15 << 8)
                            + ((((ks * 4 + grp) ^ fkey(l15))) << 4));
                v8h ah1 = *(const v8h*)((const char*)hb[hc] + ((16 + l15) << 8)
                            + ((((ks * 4 + grp) ^ fkey(16 + l15))) << 4));
                v8h bo2 = *(const v8h*)((const char*)bho + opq((hcol << 8) + ch));
                mfma_ba(acc[0][0], ah0, bh[0][ks]);
                mfma_ba(acc[1][0], ah1, bh[0][ks]);
                mfma_ba(acc[0][1], ah0, bh[1][ks]);
                mfma_ba(acc[1][1], ah1, bh[1][ks]);
                mfma_ba(acc[0][2], ah0, bh[2][ks]);
                mfma_ba(acc[1][2], ah1, bh[2][ks]);
                mfma_bv(acc[0][3], ah0, bo2);
                mfma_bv(acc[1][3], ah1, bo2);
            }
        }

        // fence: last MFMA D-write -> VALU read of acc (16 wait cycles)
        asm volatile("s_nop 7\n\ts_nop 7"
            : "+v"(acc[0][0]), "+v"(acc[0][1]), "+v"(acc[0][2]), "+v"(acc[0][3]),
              "+v"(acc[1][0]), "+v"(acc[1][1]), "+v"(acc[1][2]), "+v"(acc[1][3]));

        // gates + state update in-register; h -> LDS dbuf (fkey swizzle)
#pragma unroll
        for (int m = 0; m < 2; ++m)
#pragma unroll
            for (int r = 0; r < 4; ++r) {
                const float iv = fsig(acc[m][0][r]);
                const float fv = fsig(acc[m][1][r]);
                const float gv = ftanh(acc[m][2][r]);
                const float ov = fsig(acc[m][3][r]);
                const float c = fv * c0[m][r] + iv * gv;
                c0[m][r] = c;
                const float h = ov * ftanh(c);
                hs0[m][r] += h;
                const int b = m * 16 + grp * 4 + r;
                const int byo = (b << 8) + ((hcol << 1) ^ (fkey(b) << 4));
                *(_Float16*)((char*)hb[hc ^ 1] + byo) = (_Float16)h;
            }
        __syncthreads();   // h visible + prefetch DMA drained
        cur ^= 1; hc ^= 1;
    }

#pragma unroll
    for (int m = 0; m < 2; ++m)
#pragma unroll
        for (int r = 0; r < 4; ++r)
            hsum[((size_t)dir * NB + rb + m * 16 + grp * 4 + r) * NH + hcol] =
                hs0[m][r];
}

// ---------------------------------------------------------------------------
// k_head: pooled = hsum/T ; h1 = relu(pooled@fc1_w^T+b) ; out = h1@fc2_w^T+b
// ---------------------------------------------------------------------------
__global__ __launch_bounds__(128) void k_head(
    const float* __restrict__ hsum,
    const float* __restrict__ fc1w, const float* __restrict__ fc1b,
    const float* __restrict__ fc2w, const float* __restrict__ fc2b,
    float* __restrict__ out)
{
    __shared__ __attribute__((aligned(16))) float pooled[16][256];
    __shared__ __attribute__((aligned(16))) float h1s[16][128];
    __shared__ __attribute__((aligned(16))) char wbuf[65536];

    const int tid = threadIdx.x;
    const int rb  = blockIdx.x * 16;

    for (int i = tid; i < 16 * 256; i += 128) {
        const int r = i >> 8, c = i & 255;
        const float v = (c < 128)
            ? hsum[(size_t)(rb + r) * NH + c]
            : hsum[((size_t)NB + rb + r) * NH + (c - 128)];
        pooled[r][c] = v * (1.f / (float)NT);
    }
    for (int i = tid; i < 128 * 64; i += 128) {
        const int j = i >> 6, kq = i & 63;
        const float4 v = *(const float4*)(fc1w + (size_t)j * 256 + (kq << 2));
        v4h pv; pv[0] = (_Float16)v.x; pv[1] = (_Float16)v.y;
        pv[2] = (_Float16)v.z; pv[3] = (_Float16)v.w;
        const int byo = (j << 9) + ((kq << 3) ^ (((j >> 3) & 7) << 4));
        *(v4h*)(wbuf + byo) = pv;
    }
    __syncthreads();

    const int rgrp = tid >> 4;
    const int joct = tid & 15;
    const int r0 = rgrp * 2;
    const int j0 = joct * 8;

    float a1[2][8];
#pragma unroll
    for (int rr = 0; rr < 2; ++rr)
#pragma unroll
        for (int jo = 0; jo < 8; ++jo) a1[rr][jo] = 0.f;

    for (int kc = 0; kc < 32; ++kc) {
        const int k = kc << 3;
        float pv[2][8];
#pragma unroll
        for (int rr = 0; rr < 2; ++rr) {
            const float4 pa = *(const float4*)&pooled[r0 + rr][k];
            const float4 pb = *(const float4*)&pooled[r0 + rr][k + 4];
            pv[rr][0] = pa.x; pv[rr][1] = pa.y; pv[rr][2] = pa.z; pv[rr][3] = pa.w;
            pv[rr][4] = pb.x; pv[rr][5] = pb.y; pv[rr][6] = pb.z; pv[rr][7] = pb.w;
        }
#pragma unroll
        for (int jo = 0; jo < 8; ++jo) {
            const int j = j0 + jo;
            const int byo = (j << 9) + ((k << 1) ^ (((j >> 3) & 7) << 4));
            const v8h wv = *(const v8h*)(wbuf + byo);
#pragma unroll
            for (int i = 0; i < 8; ++i) {
                const float wf = (float)wv[i];
#pragma unroll
                for (int rr = 0; rr < 2; ++rr)
                    a1[rr][jo] += pv[rr][i] * wf;
            }
        }
    }
#pragma unroll
    for (int rr = 0; rr < 2; ++rr)
#pragma unroll
        for (int jo = 0; jo < 8; ++jo) {
            const int j = j0 + jo;
            const float v = a1[rr][jo] + fc1b[j];
            h1s[r0 + rr][j] = v > 0.f ? v : 0.f;
        }
    __syncthreads();

    for (int i = tid; i < 100 * 32; i += 128) {
        const int j = i >> 5, kq = i & 31;
        const float4 v = *(const float4*)(fc2w + (size_t)j * 128 + (kq << 2));
        const int byo = (j << 9) + ((kq << 4) ^ (((j >> 3) & 7) << 4));
        *(float4*)(wbuf + byo) = v;
    }
    __syncthreads();

    if (j0 < 100) {
        float a2[2][8];
#pragma unroll
        for (int rr = 0; rr < 2; ++rr)
#pragma unroll
            for (int jo = 0; jo < 8; ++jo) a2[rr][jo] = 0.f;

        for (int kc = 0; kc < 16; ++kc) {
            const int k = kc << 3;
            float hv[2][8];
#pragma unroll
            for (int rr = 0; rr < 2; ++rr) {
                const float4 ha = *(const float4*)&h1s[r0 + rr][k];
                const float4 hbv = *(const float4*)&h1s[r0 + rr][k + 4];
                hv[rr][0] = ha.x; hv[rr][1] = ha.y; hv[rr][2] = ha.z; hv[rr][3] = ha.w;
                hv[rr][4] = hbv.x; hv[rr][5] = hbv.y; hv[rr][6] = hbv.z; hv[rr][7] = hbv.w;
            }
#pragma unroll
            for (int jo = 0; jo < 8; ++jo) {
                const int j = j0 + jo;
                if (j < 100) {
                    const int sw = ((j >> 3) & 7) << 4;
                    const float4 wa = *(const float4*)(wbuf + (j << 9) + ((k << 2) ^ sw));
                    const float4 wb = *(const float4*)(wbuf + (j << 9) + (((k + 4) << 2) ^ sw));
#pragma unroll
                    for (int rr = 0; rr < 2; ++rr) {
                        a2[rr][jo] += hv[rr][0] * wa.x + hv[rr][1] * wa.y
                                    + hv[rr][2] * wa.z + hv[rr][3] * wa.w
                                    + hv[rr][4] * wb.x + hv[rr][5] * wb.y
                                    + hv[rr][6] * wb.z + hv[rr][7] * wb.w;
                    }
                }
            }
        }
#pragma unroll
        for (int rr = 0; rr < 2; ++rr)
#pragma unroll
            for (int jo = 0; jo < 8; ++jo) {
                const int j = j0 + jo;
                if (j < 100)
                    out[(size_t)(rb + r0 + rr) * NCLS + j] = a2[rr][jo] + fc2b[j];
            }
    }
}

// ---------------------------------------------------------------------------
extern "C" void kernel_launch(void* const* d_in, const int* in_sizes, int n_in,
                              void* d_out, int out_size, void* d_ws, size_t ws_size,
                              hipStream_t stream)
{
    (void)in_sizes; (void)n_in; (void)out_size; (void)ws_size;
    const float* x    = (const float*)d_in[0];
    const float* wihf = (const float*)d_in[1];
    const float* whhf = (const float*)d_in[2];
    const float* bihf = (const float*)d_in[3];
    const float* bhhf = (const float*)d_in[4];
    const float* wihb = (const float*)d_in[5];
    const float* whhb = (const float*)d_in[6];
    const float* bihb = (const float*)d_in[7];
    const float* bhhb = (const float*)d_in[8];
    const float* fc1w = (const float*)d_in[9];
    const float* fc1b = (const float*)d_in[10];
    const float* fc2w = (const float*)d_in[11];
    const float* fc2b = (const float*)d_in[12];
    float* out = (float*)d_out;

    char* ws = (char*)d_ws;
    float*     hs    = (float*)ws;                                    // 4 MB
    size_t off = (size_t)4 * 1024 * 1024;
    _Float16*  xh    = (_Float16*)(ws + off); off += (size_t)NB * NT * NK * 2; // 100.7 MB
    _Float16*  wt    = (_Float16*)(ws + off); off += (size_t)2 * 8 * 4 * 384 * 8 * 2;
    _Float16*  wht   = (_Float16*)(ws + off); off += (size_t)2 * 4 * 4 * 384 * 8 * 2;
    _Float16*  wh3   = (_Float16*)(ws + off); off += (size_t)2 * 128 * NK * 2;
    _Float16*  whh3  = (_Float16*)(ws + off); off += (size_t)2 * 128 * NH * 2;
    float*     bsum  = (float*)(ws + off);    off += 1024 * 4;

    k_prep<<<dim3(NB + 151), dim3(256), 0, stream>>>(
        x, wihf, wihb, whhf, whhb, bihf, bhhf, bihb, bhhb,
        xh, wt, wht, wh3, whh3, bsum);
    k_fused<<<dim3(128, 2), dim3(512), 0, stream>>>(
        xh, wt, wht, wh3, whh3, bsum, hs);
    k_head<<<dim3(256), dim3(128), 0, stream>>>(hs, fc1w, fc1b, fc2w, fc2b, out);
}

// Round 17
// 267.043 us; speedup vs baseline: 1.0679x; 1.0679x over previous
//
#include <hip/hip_runtime.h>
#include <stdint.h>

#define NB 4096
#define NT 48
#define NF 225
#define NH 128
#define NG 512   // 4*H
#define NK 256   // K padded 225->256
#define NCLS 100

typedef __attribute__((ext_vector_type(8))) _Float16 v8h;
typedef __attribute__((ext_vector_type(4))) _Float16 v4h;
typedef __attribute__((ext_vector_type(4))) float v4f;

__device__ __forceinline__ float fsig(float x) {
    return __builtin_amdgcn_rcpf(1.f + __expf(-x));
}
__device__ __forceinline__ float ftanh(float x) {
    return 2.f * __builtin_amdgcn_rcpf(1.f + __expf(-2.f * x)) - 1.f;
}
// keep loop-invariant LDS-B addresses from being hoisted (register budget!)
__device__ __forceinline__ int opq(int x) { asm volatile("" : "+v"(x)); return x; }

// MFMA via inline asm: acc in VGPR, B pinned in AGPR (non-rematerializable)
__device__ __forceinline__ void mfma_ba(v4f& c, v8h a, v8h b) {
    asm volatile("v_mfma_f32_16x16x32_f16 %0, %1, %2, %0"
                 : "+v"(c) : "v"(a), "a"(b));
}
// MFMA with B streamed from LDS (VGPR)
__device__ __forceinline__ void mfma_bv(v4f& c, v8h a, v8h b) {
    asm volatile("v_mfma_f32_16x16x32_f16 %0, %1, %2, %0"
                 : "+v"(c) : "v"(a), "v"(b));
}

// global -> LDS direct copy, 16B per lane (dest = wave-uniform base + lane*16).
__device__ __forceinline__ void gld16(const void* g, void* l) {
    __builtin_amdgcn_global_load_lds(
        (const __attribute__((address_space(1))) void*)g,
        (__attribute__((address_space(3))) void*)l, 16, 0, 0);
}

// ---------------------------------------------------------------------------
// k_prep:
//  xh[t][b][256]   fp16, zero-padded, 16B chunks XOR-swizzled by (b&7)
//  wt[dir][8ks][4grp][384n][8]  k-major transposed w_ih (gates i,f,g) fp16
//  wht[dir][4ks][4grp][384n][8] k-major transposed w_hh (gates i,f,g) fp16
//  wh3[dir][128][256]  gate-o w_ih rows, chunk-swizzled by (col&7)  (LDS copy)
//  whh3[dir][128][128] gate-o w_hh rows, chunk-swizzled by (col&7)
//  bsum[dir][512] = b_ih + b_hh (fp32)
// ---------------------------------------------------------------------------
__global__ __launch_bounds__(256) void k_prep(
    const float* __restrict__ x,
    const float* __restrict__ wihf, const float* __restrict__ wihb,
    const float* __restrict__ whhf, const float* __restrict__ whhb,
    const float* __restrict__ bihf, const float* __restrict__ bhhf,
    const float* __restrict__ bihb, const float* __restrict__ bhhb,
    _Float16* __restrict__ xh, _Float16* __restrict__ wt,
    _Float16* __restrict__ wht, _Float16* __restrict__ wh3,
    _Float16* __restrict__ whh3, float* __restrict__ bsum)
{
    __shared__ __attribute__((aligned(16))) _Float16 ls[NT * NF + 16];
    const int bid = blockIdx.x;
    const int tid = threadIdx.x;

    if (bid < NB) {
        const float* src = x + (size_t)bid * (NT * NF);   // 43200B contiguous
        for (int i = tid; i < (NT * NF) / 4; i += 256) {
            const float4 v = ((const float4*)src)[i];
            v4h hv; hv[0] = (_Float16)v.x; hv[1] = (_Float16)v.y;
            hv[2] = (_Float16)v.z; hv[3] = (_Float16)v.w;
            *(v4h*)(ls + i * 4) = hv;
        }
        __syncthreads();
        const int key = bid & 7;
        for (int task = tid; task < NT * 32; task += 256) {
            const int t = task >> 5, c = task & 31;
            v8h hv;
#pragma unroll
            for (int e = 0; e < 8; ++e) {
                const int k = c * 8 + e;
                hv[e] = (k < NF) ? ls[t * NF + k] : (_Float16)0.f;
            }
            *(v8h*)(xh + ((size_t)t * NB + bid) * NK + ((c ^ key) << 3)) = hv;
        }
    } else if (bid < NB + 96) {
        // wt: 24576 v8h rows [dir][ks 0..7][grp 0..3][n 0..383]
        const int task = (bid - NB) * 256 + tid;
        const int n = task % 384;
        const int r2 = task / 384;          // 0..63
        const int grp = r2 & 3, ks = (r2 >> 2) & 7, dir = r2 >> 5;
        const float* src = (dir ? wihb : wihf) + (size_t)n * NF;
        v8h hv;
#pragma unroll
        for (int e = 0; e < 8; ++e) {
            const int k = ks * 32 + grp * 8 + e;
            hv[e] = (k < NF) ? (_Float16)src[k] : (_Float16)0.f;
        }
        *(v8h*)(wt + (size_t)task * 8) = hv;
    } else if (bid < NB + 144) {
        // wht: 12288 v8h rows [dir][ks 0..3][grp 0..3][n 0..383]
        const int task = (bid - NB - 96) * 256 + tid;
        const int n = task % 384;
        const int r2 = task / 384;          // 0..31
        const int grp = r2 & 3, ks = (r2 >> 2) & 3, dir = r2 >> 4;
        const float* src = (dir ? whhb : whhf) + (size_t)n * NH + ks * 32 + grp * 8;
        v8h hv;
#pragma unroll
        for (int e = 0; e < 8; ++e) hv[e] = (_Float16)src[e];
        *(v8h*)(wht + (size_t)task * 8) = hv;
    } else if (bid < NB + 148) {
        // wh3: gate-o (rows 384..511) of w_ih, chunk-swizzled by (col&7)
        for (int s = 0; s < 8; ++s) {
            const int task = (bid - NB - 144) * 2048 + s * 256 + tid; // 0..8191
            const int dir = task >> 12;
            const int rem = task & 4095;
            const int col = rem >> 5, c = rem & 31;
            const float* src = (dir ? wihb : wihf) + (size_t)(384 + col) * NF + c * 8;
            v8h hv;
#pragma unroll
            for (int e = 0; e < 8; ++e) {
                const int k = c * 8 + e;
                hv[e] = (k < NF) ? (_Float16)src[e] : (_Float16)0.f;
            }
            *(v8h*)(wh3 + ((size_t)dir * 128 + col) * NK + ((c ^ (col & 7)) << 3)) = hv;
        }
    } else if (bid < NB + 150) {
        // whh3: gate-o (rows 384..511) of w_hh, chunk-swizzled by (col&7)
        for (int s = 0; s < 8; ++s) {
            const int task = (bid - NB - 148) * 2048 + s * 256 + tid; // 0..4095
            const int dir = task >> 11;
            const int rem = task & 2047;
            const int col = rem >> 4, c = rem & 15;
            const float* src = (dir ? whhb : whhf) + (size_t)(384 + col) * NH + c * 8;
            v8h hv;
#pragma unroll
            for (int e = 0; e < 8; ++e) hv[e] = (_Float16)src[e];
            *(v8h*)(whh3 + ((size_t)dir * 128 + col) * NH + ((c ^ (col & 7)) << 3)) = hv;
        }
    } else {
        for (int i = tid; i < 1024; i += 256) {
            const int dir = i >> 9, n = i & 511;
            bsum[i] = dir ? (bihb[n] + bhhb[n]) : (bihf[n] + bhhf[n]);
        }
    }
}

// ---------------------------------------------------------------------------
// k_fused: input GEMM + LSTM recurrence + hsum, one dispatch.
// Block = 32 b-rows x dir, 512 thr (8 waves), 1 block/CU (2 waves/SIMD ->
// 256 unified regs/wave). Wave owns hcol = w*16+l15, all 4 gates.
// Gates i,f,g: 36 B-fragments pinned in AGPRs (asm defs, non-rematable);
// inline-asm MFMA reads B directly from AGPR -- zero per-step copies.
// acc in VGPR. Hazard fences (reg-carried s_nop) guard the two
// INLINEASM boundaries the compiler's hazard recognizer cannot see:
// VALU acc-init -> MFMA srcC, and MFMA D-write -> combine VALU read.
// Gate o: B streamed from LDS.
// ---------------------------------------------------------------------------
__global__ void __launch_bounds__(512, 2) k_fused(
    const _Float16* __restrict__ xh,     // [48][4096][256] swizzled (b&7)
    const _Float16* __restrict__ wt,     // [2][8][4][384][8]
    const _Float16* __restrict__ wht,    // [2][4][4][384][8]
    const _Float16* __restrict__ wh3,    // [2][128][256] swizzled (col&7)
    const _Float16* __restrict__ whh3,   // [2][128][128] swizzled (col&7)
    const float* __restrict__ bsum,      // [2][512]
    float* __restrict__ hsum)            // [2][4096][128]
{
    __shared__ __attribute__((aligned(16))) _Float16 xb[2][32 * 256]; // 32KB
    __shared__ __attribute__((aligned(16))) _Float16 hb[2][32 * 128]; // 16KB
    __shared__ __attribute__((aligned(16))) _Float16 bxo[128 * 256];  // 64KB
    __shared__ __attribute__((aligned(16))) _Float16 bho[128 * 128];  // 32KB

    const int tid   = threadIdx.x;
    const int btile = blockIdx.x;        // 0..127
    const int dir   = blockIdx.y;
    const int rb    = btile * 32;
    const int lane  = tid & 63;
    const int w     = tid >> 6;          // 0..7
    const int l15   = lane & 15;
    const int grp   = lane >> 4;
    const int hcol  = w * 16 + l15;      // 0..127
    const int swz   = hcol & 7;

    // one-time LDS preload of gate-o weights (pre-swizzled source, DMA)
#pragma unroll
    for (int j = 0; j < 12; ++j) {
        const int seg = w + j * 8;       // 0..95
        if (seg < 64)
            gld16((const char*)wh3 + (size_t)dir * 65536 + (seg << 10) + lane * 16,
                  (char*)bxo + (seg << 10));
        else
            gld16((const char*)whh3 + (size_t)dir * 32768 + ((seg - 64) << 10) + lane * 16,
                  (char*)bho + ((seg - 64) << 10));
    }

    // persistent B fragments: gates 0..2 (i,f,g), pinned into AGPRs once.
    v8h bx[3][8], bh[3][4];
#pragma unroll
    for (int g = 0; g < 3; ++g) {
#pragma unroll
        for (int ks = 0; ks < 8; ++ks) {
            bx[g][ks] = *(const v8h*)(wt +
                ((((size_t)dir * 8 + ks) * 4 + grp) * 384 + g * 128 + hcol) * 8);
            asm volatile("" : "+a"(bx[g][ks]));
        }
#pragma unroll
        for (int ks = 0; ks < 4; ++ks) {
            bh[g][ks] = *(const v8h*)(wht +
                ((((size_t)dir * 4 + ks) * 4 + grp) * 384 + g * 128 + hcol) * 8);
            asm volatile("" : "+a"(bh[g][ks]));
        }
    }
    float bias[4];
#pragma unroll
    for (int g = 0; g < 4; ++g)
        bias[g] = bsum[dir * NG + g * NH + hcol];

    float c0[2][4], hs0[2][4];
#pragma unroll
    for (int m = 0; m < 2; ++m)
#pragma unroll
        for (int r = 0; r < 4; ++r) { c0[m][r] = 0.f; hs0[m][r] = 0.f; }

    auto stage = [&](int tx, int buf) {
        const char* src = (const char*)(xh + ((size_t)tx * NB + rb) * NK);
#pragma unroll
        for (int c = 0; c < 2; ++c) {
            const int seg = w * 2 + c;            // 16 x 1KB segments
            gld16(src + (seg << 10) + lane * 16, (char*)xb[buf] + (seg << 10));
        }
    };

    stage(dir ? (NT - 1) : 0, 0);
    __syncthreads();   // preloads + stage drained

    int cur = 0, hc = 0;
#pragma unroll 1
    for (int t = 0; t < NT; ++t) {
        if (t + 1 < NT)
            stage(dir ? (NT - 2 - t) : (t + 1), cur ^ 1);   // async prefetch

        v4f acc[2][4];
#pragma unroll
        for (int m = 0; m < 2; ++m)
#pragma unroll
            for (int g = 0; g < 4; ++g)
                acc[m][g] = (v4f){bias[g], bias[g], bias[g], bias[g]};

        // fence: VALU acc-init -> MFMA srcC read (hazard recognizer can't
        // see into INLINEASM; carry all accs as operands to pin ordering)
        asm volatile("s_nop 2"
            : "+v"(acc[0][0]), "+v"(acc[0][1]), "+v"(acc[0][2]), "+v"(acc[0][3]),
              "+v"(acc[1][0]), "+v"(acc[1][1]), "+v"(acc[1][2]), "+v"(acc[1][3]));

        // x-part: K=256 in 8 slices; gates 0-2 AGPR-B, gate 3 LDS-B
#pragma unroll
        for (int ks = 0; ks < 8; ++ks) {
            const int ch = ((ks * 4 + grp) ^ swz) << 4;
            v8h af0 = *(const v8h*)((const char*)xb[cur] + (l15 << 9)
                        + ((((ks * 4 + grp) ^ (l15 & 7))) << 4));
            v8h af1 = *(const v8h*)((const char*)xb[cur] + ((16 + l15) << 9)
                        + ((((ks * 4 + grp) ^ (l15 & 7))) << 4));
            v8h bo = *(const v8h*)((const char*)bxo + opq((hcol << 9) + ch));
            mfma_ba(acc[0][0], af0, bx[0][ks]);
            mfma_ba(acc[1][0], af1, bx[0][ks]);
            mfma_ba(acc[0][1], af0, bx[1][ks]);
            mfma_ba(acc[1][1], af1, bx[1][ks]);
            mfma_ba(acc[0][2], af0, bx[2][ks]);
            mfma_ba(acc[1][2], af1, bx[2][ks]);
            mfma_bv(acc[0][3], af0, bo);
            mfma_bv(acc[1][3], af1, bo);
        }

        // h-part: K=128 in 4 slices
        if (t > 0) {
#pragma unroll
            for (int ks = 0; ks < 4; ++ks) {
                const int ch = ((ks * 4 + grp) ^ swz) << 4;
                v8h ah0 = *(const v8h*)((const char*)hb[hc] + (l15 << 8)
                            + ((((ks * 4 + grp) ^ (l15 & 7))) << 4));
                v8h ah1 = *(const v8h*)((const char*)hb[hc] + ((16 + l15) << 8)
                            + ((((ks * 4 + grp) ^ (l15 & 7))) << 4));
                v8h bo2 = *(const v8h*)((const char*)bho + opq((hcol << 8) + ch));
                mfma_ba(acc[0][0], ah0, bh[0][ks]);
                mfma_ba(acc[1][0], ah1, bh[0][ks]);
                mfma_ba(acc[0][1], ah0, bh[1][ks]);
                mfma_ba(acc[1][1], ah1, bh[1][ks]);
                mfma_ba(acc[0][2], ah0, bh[2][ks]);
                mfma_ba(acc[1][2], ah1, bh[2][ks]);
                mfma_bv(acc[0][3], ah0, bo2);
                mfma_bv(acc[1][3], ah1, bo2);
            }
        }

        // fence: last MFMA D-write -> VALU read of acc (16 wait cycles)
        asm volatile("s_nop 7\n\ts_nop 7"
            : "+v"(acc[0][0]), "+v"(acc[0][1]), "+v"(acc[0][2]), "+v"(acc[0][3]),
              "+v"(acc[1][0]), "+v"(acc[1][1]), "+v"(acc[1][2]), "+v"(acc[1][3]));

        // gates + state update in-register; h -> LDS dbuf (swizzled)
#pragma unroll
        for (int m = 0; m < 2; ++m)
#pragma unroll
            for (int r = 0; r < 4; ++r) {
                const float iv = fsig(acc[m][0][r]);
                const float fv = fsig(acc[m][1][r]);
                const float gv = ftanh(acc[m][2][r]);
                const float ov = fsig(acc[m][3][r]);
                const float c = fv * c0[m][r] + iv * gv;
                c0[m][r] = c;
                const float h = ov * ftanh(c);
                hs0[m][r] += h;
                const int b = m * 16 + grp * 4 + r;
                const int byo = (b << 8) + ((hcol << 1) ^ ((b & 7) << 4));
                *(_Float16*)((char*)hb[hc ^ 1] + byo) = (_Float16)h;
            }
        __syncthreads();   // h visible + prefetch DMA drained
        cur ^= 1; hc ^= 1;
    }

#pragma unroll
    for (int m = 0; m < 2; ++m)
#pragma unroll
        for (int r = 0; r < 4; ++r)
            hsum[((size_t)dir * NB + rb + m * 16 + grp * 4 + r) * NH + hcol] =
                hs0[m][r];
}

// ---------------------------------------------------------------------------
// k_head: pooled = hsum/T ; h1 = relu(pooled@fc1_w^T+b) ; out = h1@fc2_w^T+b
// ---------------------------------------------------------------------------
__global__ __launch_bounds__(128) void k_head(
    const float* __restrict__ hsum,
    const float* __restrict__ fc1w, const float* __restrict__ fc1b,
    const float* __restrict__ fc2w, const float* __restrict__ fc2b,
    float* __restrict__ out)
{
    __shared__ __attribute__((aligned(16))) float pooled[16][256];
    __shared__ __attribute__((aligned(16))) float h1s[16][128];
    __shared__ __attribute__((aligned(16))) char wbuf[65536];

    const int tid = threadIdx.x;
    const int rb  = blockIdx.x * 16;

    for (int i = tid; i < 16 * 256; i += 128) {
        const int r = i >> 8, c = i & 255;
        const float v = (c < 128)
            ? hsum[(size_t)(rb + r) * NH + c]
            : hsum[((size_t)NB + rb + r) * NH + (c - 128)];
        pooled[r][c] = v * (1.f / (float)NT);
    }
    for (int i = tid; i < 128 * 64; i += 128) {
        const int j = i >> 6, kq = i & 63;
        const float4 v = *(const float4*)(fc1w + (size_t)j * 256 + (kq << 2));
        v4h pv; pv[0] = (_Float16)v.x; pv[1] = (_Float16)v.y;
        pv[2] = (_Float16)v.z; pv[3] = (_Float16)v.w;
        const int byo = (j << 9) + ((kq << 3) ^ (((j >> 3) & 7) << 4));
        *(v4h*)(wbuf + byo) = pv;
    }
    __syncthreads();

    const int rgrp = tid >> 4;
    const int joct = tid & 15;
    const int r0 = rgrp * 2;
    const int j0 = joct * 8;

    float a1[2][8];
#pragma unroll
    for (int rr = 0; rr < 2; ++rr)
#pragma unroll
        for (int jo = 0; jo < 8; ++jo) a1[rr][jo] = 0.f;

    for (int kc = 0; kc < 32; ++kc) {
        const int k = kc << 3;
        float pv[2][8];
#pragma unroll
        for (int rr = 0; rr < 2; ++rr) {
            const float4 pa = *(const float4*)&pooled[r0 + rr][k];
            const float4 pb = *(const float4*)&pooled[r0 + rr][k + 4];
            pv[rr][0] = pa.x; pv[rr][1] = pa.y; pv[rr][2] = pa.z; pv[rr][3] = pa.w;
            pv[rr][4] = pb.x; pv[rr][5] = pb.y; pv[rr][6] = pb.z; pv[rr][7] = pb.w;
        }
#pragma unroll
        for (int jo = 0; jo < 8; ++jo) {
            const int j = j0 + jo;
            const int byo = (j << 9) + ((k << 1) ^ (((j >> 3) & 7) << 4));
            const v8h wv = *(const v8h*)(wbuf + byo);
#pragma unroll
            for (int i = 0; i < 8; ++i) {
                const float wf = (float)wv[i];
#pragma unroll
                for (int rr = 0; rr < 2; ++rr)
                    a1[rr][jo] += pv[rr][i] * wf;
            }
        }
    }
#pragma unroll
    for (int rr = 0; rr < 2; ++rr)
#pragma unroll
        for (int jo = 0; jo < 8; ++jo) {
            const int j = j0 + jo;
            const float v = a1[rr][jo] + fc1b[j];
            h1s[r0 + rr][j] = v > 0.f ? v : 0.f;
        }
    __syncthreads();

    for (int i = tid; i < 100 * 32; i += 128) {
        const int j = i >> 5, kq = i & 31;
        const float4 v = *(const float4*)(fc2w + (size_t)j * 128 + (kq << 2));
        const int byo = (j << 9) + ((kq << 4) ^ (((j >> 3) & 7) << 4));
        *(float4*)(wbuf + byo) = v;
    }
    __syncthreads();

    if (j0 < 100) {
        float a2[2][8];
#pragma unroll
        for (int rr = 0; rr < 2; ++rr)
#pragma unroll
            for (int jo = 0; jo < 8; ++jo) a2[rr][jo] = 0.f;

        for (int kc = 0; kc < 16; ++kc) {
            const int k = kc << 3;
            float hv[2][8];
#pragma unroll
            for (int rr = 0; rr < 2; ++rr) {
                const float4 ha = *(const float4*)&h1s[r0 + rr][k];
                const float4 hbv = *(const float4*)&h1s[r0 + rr][k + 4];
                hv[rr][0] = ha.x; hv[rr][1] = ha.y; hv[rr][2] = ha.z; hv[rr][3] = ha.w;
                hv[rr][4] = hbv.x; hv[rr][5] = hbv.y; hv[rr][6] = hbv.z; hv[rr][7] = hbv.w;
            }
#pragma unroll
            for (int jo = 0; jo < 8; ++jo) {
                const int j = j0 + jo;
                if (j < 100) {
                    const int sw = ((j >> 3) & 7) << 4;
                    const float4 wa = *(const float4*)(wbuf + (j << 9) + ((k << 2) ^ sw));
                    const float4 wb = *(const float4*)(wbuf + (j << 9) + (((k + 4) << 2) ^ sw));
#pragma unroll
                    for (int rr = 0; rr < 2; ++rr) {
                        a2[rr][jo] += hv[rr][0] * wa.x + hv[rr][1] * wa.y
                                    + hv[rr][2] * wa.z + hv[rr][3] * wa.w
                                    + hv[rr][4] * wb.x + hv[rr][5] * wb.y
                                    + hv[rr][6] * wb.z + hv[rr][7] * wb.w;
                    }
                }
            }
        }
#pragma unroll
        for (int rr = 0; rr < 2; ++rr)
#pragma unroll
            for (int jo = 0; jo < 8; ++jo) {
                const int j = j0 + jo;
                if (j < 100)
                    out[(size_t)(rb + r0 + rr) * NCLS + j] = a2[rr][jo] + fc2b[j];
            }
    }
}

// ---------------------------------------------------------------------------
extern "C" void kernel_launch(void* const* d_in, const int* in_sizes, int n_in,
                              void* d_out, int out_size, void* d_ws, size_t ws_size,
                              hipStream_t stream)
{
    (void)in_sizes; (void)n_in; (void)out_size; (void)ws_size;
    const float* x    = (const float*)d_in[0];
    const float* wihf = (const float*)d_in[1];
    const float* whhf = (const float*)d_in[2];
    const float* bihf = (const float*)d_in[3];
    const float* bhhf = (const float*)d_in[4];
    const float* wihb = (const float*)d_in[5];
    const float* whhb = (const float*)d_in[6];
    const float* bihb = (const float*)d_in[7];
    const float* bhhb = (const float*)d_in[8];
    const float* fc1w = (const float*)d_in[9];
    const float* fc1b = (const float*)d_in[10];
    const float* fc2w = (const float*)d_in[11];
    const float* fc2b = (const float*)d_in[12];
    float* out = (float*)d_out;

    char* ws = (char*)d_ws;
    float*     hs    = (float*)ws;                                    // 4 MB
    size_t off = (size_t)4 * 1024 * 1024;
    _Float16*  xh    = (_Float16*)(ws + off); off += (size_t)NB * NT * NK * 2; // 100.7 MB
    _Float16*  wt    = (_Float16*)(ws + off); off += (size_t)2 * 8 * 4 * 384 * 8 * 2;
    _Float16*  wht   = (_Float16*)(ws + off); off += (size_t)2 * 4 * 4 * 384 * 8 * 2;
    _Float16*  wh3   = (_Float16*)(ws + off); off += (size_t)2 * 128 * NK * 2;
    _Float16*  whh3  = (_Float16*)(ws + off); off += (size_t)2 * 128 * NH * 2;
    float*     bsum  = (float*)(ws + off);    off += 1024 * 4;

    k_prep<<<dim3(NB + 151), dim3(256), 0, stream>>>(
        x, wihf, wihb, whhf, whhb, bihf, bhhf, bihb, bhhb,
        xh, wt, wht, wh3, whh3, bsum);
    k_fused<<<dim3(128, 2), dim3(512), 0, stream>>>(
        xh, wt, wht, wh3, whh3, bsum, hs);
    k_head<<<dim3(256), dim3(128), 0, stream>>>(hs, fc1w, fc1b, fc2w, fc2b, out);
}